// Round 14
// baseline (1994.973 us; speedup 1.0000x reference)
//
#include <hip/hip_runtime.h>
#include <cmath>

#define Bn   128
#define Cn   8
#define Fn   58
#define Tn   249
#define RCn  24
#define FT   14442      // Fn*Tn
#define CFT  115536     // Cn*Fn*Tn
#define OUTB 346608     // 3*CFT per-batch output
#define IH   60
#define IW   251

// ---------------------------------------------------------------------------
// differ = concat([x[...,:1], W_diff@x + b_diff (shift) - x[...,:-1]], -1)
// Q = wq@differ + bq ; K = wk@differ + bk ; V = differ
// ---------------------------------------------------------------------------
__global__ void __launch_bounds__(256)
k_differ_qk(const float* __restrict__ x,
            const float* __restrict__ w_diff, const float* __restrict__ b_diff,
            const float* __restrict__ wq, const float* __restrict__ bq,
            const float* __restrict__ wk, const float* __restrict__ bk,
            float* __restrict__ V, float* __restrict__ Q, float* __restrict__ K) {
    int t = threadIdx.x;
    if (t >= Tn) return;
    int f  = blockIdx.y;
    int b  = blockIdx.z;
    int ft = f * Tn + t;
    const float* xb = x + (size_t)b * CFT + ft;

    float xv[Cn], d[Cn];
    #pragma unroll
    for (int c = 0; c < Cn; c++) xv[c] = xb[c * FT];

    if (t == 0) {
        #pragma unroll
        for (int c = 0; c < Cn; c++) d[c] = xv[c];
    } else {
        #pragma unroll
        for (int o = 0; o < Cn; o++) {
            float s = b_diff[o];
            #pragma unroll
            for (int c = 0; c < Cn; c++) s += w_diff[o * Cn + c] * xv[c];
            d[o] = s - xb[o * FT - 1];
        }
    }

    float* Vb = V + (size_t)b * CFT + ft;
    float* Qb = Q + (size_t)b * CFT + ft;
    float* Kb = K + (size_t)b * CFT + ft;
    #pragma unroll
    for (int o = 0; o < Cn; o++) {
        Vb[o * FT] = d[o];
        float q = bq[o], k = bk[o];
        #pragma unroll
        for (int c = 0; c < Cn; c++) { q += wq[o * Cn + c] * d[c]; k += wk[o * Cn + c] * d[c]; }
        Qb[o * FT] = q;
        Kb[o * FT] = k;
    }
}

// ---------------------------------------------------------------------------
// Column-owner register GEMM (v7 body).
// ---------------------------------------------------------------------------
template<int AN, int RG, int GW, int VL>
__global__ void __launch_bounds__(256, 4)
k_gemm(const float* __restrict__ A, long long aStride, int aLd,
       const float* __restrict__ bias,
       const float* __restrict__ V, long long vStride, int dv,
       float* __restrict__ out, long long oStride, int add,
       int gx, int gy)
{
    constexpr int TPG = 256 / GW;
    constexpr int RGA = (RG + 3) & ~3;
    constexpr int RGP = GW * RGA + 4;    // 16B-aligned row stride
    __shared__ float As[64][RGP];

    int nblk = gridDim.x;
    int bid  = blockIdx.x;
    if ((nblk & 7) == 0) {               // bijective XCD swizzle
        int cpx = nblk >> 3;
        bid = (bid & 7) * cpx + (bid >> 3);
    }
    int gxy = gx * gy;
    int b   = bid / gxy;
    int rem = bid - b * gxy;
    int jb  = (rem / gx) * (GW * RG);
    int g   = threadIdx.x / TPG;         // wave-aligned group id
    int cl  = threadIdx.x % TPG;
    int j0  = jb + g * RG;
    int l   = (rem % gx) * (TPG * VL) + cl * VL;
    bool act = (l + VL <= dv);

    const float* Ab = A + (size_t)b * aStride;
    const float* Vb = V + (size_t)b * vStride + l;

    float acc[RG][VL];
    #pragma unroll
    for (int j = 0; j < RG; j++)
        #pragma unroll
        for (int e = 0; e < VL; e++) acc[j][e] = 0.f;

    for (int m0 = 0; m0 < AN; m0 += 64) {
        int mc = min(64, AN - m0);
        for (int idx = threadIdx.x; idx < GW * RG * 64; idx += 256) {
            int j = idx >> 6, mi = idx & 63;
            float w = 0.f;
            if (jb + j < AN && mi < mc) w = Ab[(size_t)(jb + j) * aLd + m0 + mi];
            As[mi][(j / RG) * RGA + (j % RG)] = w;
        }
        __syncthreads();
        if (act) {
            const float* Vp = Vb + (size_t)m0 * dv;
            auto LD = [&](int i) -> float4 {
                const float* p = Vp + (size_t)i * dv;     // affine
                if constexpr (VL == 4) {
                    return *(const float4*)p;
                } else {
                    float2 t = *(const float2*)p;
                    return make_float4(t.x, t.y, 0.f, 0.f);
                }
            };
            auto FMA = [&](int mm, float4 x) {
                const float* w = &As[mm][g * RGA];
                #pragma unroll
                for (int j = 0; j < RG; j++) {
                    float wv = w[j];
                    acc[j][0] += wv * x.x;
                    if constexpr (VL >= 2) acc[j][1] += wv * x.y;
                    if constexpr (VL >= 4) {
                        acc[j][2] += wv * x.z;
                        acc[j][3] += wv * x.w;
                    }
                }
            };
            float4 p0 = LD(0), p1 = LD(1), p2 = LD(2), p3 = LD(3);
            int mm = 0;
            for (; mm + 4 <= mc; mm += 4) {
                FMA(mm + 0, p0); p0 = LD(mm + 4);
                FMA(mm + 1, p1); p1 = LD(mm + 5);
                FMA(mm + 2, p2); p2 = LD(mm + 6);
                FMA(mm + 3, p3); p3 = LD(mm + 7);
            }
            if (mm     < mc) FMA(mm,     p0);
            if (mm + 1 < mc) FMA(mm + 1, p1);
            if (mm + 2 < mc) FMA(mm + 2, p2);
        }
        __syncthreads();
    }

    if (!act) return;
    float* ob = out + (size_t)b * oStride + l;
    #pragma unroll
    for (int j = 0; j < RG; j++) {
        if (j0 + j < AN) {
            float bv = bias ? bias[j0 + j] : 0.f;
            float* op = ob + (size_t)(j0 + j) * dv;
            if (add) {
                #pragma unroll
                for (int e = 0; e < VL; e++) op[e] += acc[j][e] + bv;
            } else {
                if constexpr (VL == 4) {
                    *(float4*)op = make_float4(acc[j][0] + bv, acc[j][1] + bv,
                                               acc[j][2] + bv, acc[j][3] + bv);
                } else {
                    *(float2*)op = make_float2(acc[j][0] + bv, acc[j][1] + bv);
                }
            }
        }
    }
}

// ---------------------------------------------------------------------------
// Stride-2 conv v10: R11 body with the prefetch clamp removed — SINGLE path,
// unclamped affine loads (same mechanism as k_gemm's LD, proven spill-free
// since R7). Strictly fewer live values than the clamped version, so the
// R10/R12 spill mechanism cannot trigger. OOB prefetch rows (last chunk /
// last batch) land in adjacent workspace regions and are never accumulated.
// RGW=4 / gy=16 FROZEN (R10: RGW=8 spilled; R12: dual-path spilled).
// ---------------------------------------------------------------------------
template<int AN, int RGW>
__global__ void __launch_bounds__(256, 4)
k_gemm_s2(const float* __restrict__ W, const float* __restrict__ bias,
          const float* __restrict__ X, long long xStride, int d_in, int d_out,
          float* __restrict__ out, long long oStride, int gy)
{
    constexpr int BR = 4 * RGW;
    __shared__ float Ws[64][2 * BR + 4];

    int nblk = gridDim.x;
    int bid  = blockIdx.x;
    if ((nblk & 7) == 0) {
        int cpx = nblk >> 3;
        bid = (bid & 7) * cpx + (bid >> 3);
    }
    int b    = bid / gy;
    int jb   = (bid % gy) * BR;
    int w    = threadIdx.x >> 6;
    int lane = threadIdx.x & 63;
    int j0   = jb + w * RGW;
    int l4   = lane * 4;
    bool act = l4 < d_out;                   // d_out=232 -> lanes 0..57

    const float* Xb = X + (size_t)b * xStride + 2 * l4;

    float acc[RGW][4];
    #pragma unroll
    for (int j = 0; j < RGW; j++)
        #pragma unroll
        for (int e = 0; e < 4; e++) acc[j][e] = 0.f;

    for (int m0 = 0; m0 < AN; m0 += 64) {
        int mc = min(64, AN - m0);
        for (int idx = threadIdx.x; idx < 2 * BR * 64; idx += 256) {
            int mi = idx & 63, rest = idx >> 6;
            int rj = rest >> 1, tap = rest & 1;
            float wv = 0.f;
            if (jb + rj < AN && mi < mc)
                wv = W[((size_t)(jb + rj) * AN + m0 + mi) * 2 + tap];
            Ws[mi][2 * rj + tap] = wv;
        }
        __syncthreads();
        if (act) {
            const float* Xp = Xb + (size_t)m0 * d_in;
            auto FMAS = [&](int mm, float4 x0, float4 x1) {
                const float* wrow = &Ws[mm][2 * (w * RGW)];
                #pragma unroll
                for (int j = 0; j < RGW; j++) {
                    float w0 = wrow[2 * j], w1 = wrow[2 * j + 1];
                    acc[j][0] += w0 * x0.x + w1 * x0.y;
                    acc[j][1] += w0 * x0.z + w1 * x0.w;
                    acc[j][2] += w0 * x1.x + w1 * x1.y;
                    acc[j][3] += w0 * x1.z + w1 * x1.w;
                }
            };
            auto LDP = [&](int i, float4& a, float4& bb) {
                const float* p = Xp + (size_t)i * d_in;   // affine, unclamped
                a = *(const float4*)p; bb = *(const float4*)(p + 4);
            };
            float4 a0, b0, a1, b1, a2, b2, a3, b3;
            LDP(0, a0, b0); LDP(1, a1, b1); LDP(2, a2, b2); LDP(3, a3, b3);
            int mm = 0;
            for (; mm + 4 <= mc; mm += 4) {
                FMAS(mm + 0, a0, b0); LDP(mm + 4, a0, b0);
                FMAS(mm + 1, a1, b1); LDP(mm + 5, a1, b1);
                FMAS(mm + 2, a2, b2); LDP(mm + 6, a2, b2);
                FMAS(mm + 3, a3, b3); LDP(mm + 7, a3, b3);
            }
            if (mm     < mc) FMAS(mm,     a0, b0);
            if (mm + 1 < mc) FMAS(mm + 1, a1, b1);
            if (mm + 2 < mc) FMAS(mm + 2, a2, b2);
        }
        __syncthreads();
    }

    if (!act) return;
    float* ob = out + (size_t)b * oStride + l4;
    #pragma unroll
    for (int j = 0; j < RGW; j++) {
        if (j0 + j < AN) {
            float bv = bias[j0 + j];
            *(float4*)(ob + (size_t)(j0 + j) * d_out) =
                make_float4(acc[j][0] + bv, acc[j][1] + bv,
                            acc[j][2] + bv, acc[j][3] + bv);
        }
    }
}

// ---------------------------------------------------------------------------
// t-branch scores: 128x128 tile, 8x8 per thread.
// ---------------------------------------------------------------------------
__global__ void __launch_bounds__(256, 4)
k_scores128(const float* __restrict__ Q, const float* __restrict__ K,
            float* __restrict__ S, int n, int d, int sQ) {
    __shared__ float Qs[16][132];
    __shared__ float Ks[16][132];
    int b  = blockIdx.z;
    int r0 = blockIdx.x * 128, c0 = blockIdx.y * 128;
    int tid = threadIdx.x;
    int tx = tid & 15, ty = tid >> 4;
    int lrow = tid >> 1;
    int lk   = (tid & 1) * 8;
    const float* Qr = Q + (size_t)b * sQ + (size_t)min(r0 + lrow, n - 1) * d;
    const float* Kr = K + (size_t)b * sQ + (size_t)min(c0 + lrow, n - 1) * d;

    float acc[8][8] = {};
    for (int kk = 0; kk < d; kk += 16) {
        #pragma unroll
        for (int h = 0; h < 2; h++) {
            int g = kk + lk + h * 4;
            float4 qv = make_float4(0.f, 0.f, 0.f, 0.f);
            float4 kv = make_float4(0.f, 0.f, 0.f, 0.f);
            if (g + 4 <= d) {                 // d % 4 == 0 for all uses
                qv = *(const float4*)(Qr + g);
                kv = *(const float4*)(Kr + g);
            }
            int kb = lk + h * 4;
            Qs[kb + 0][lrow] = qv.x; Qs[kb + 1][lrow] = qv.y;
            Qs[kb + 2][lrow] = qv.z; Qs[kb + 3][lrow] = qv.w;
            Ks[kb + 0][lrow] = kv.x; Ks[kb + 1][lrow] = kv.y;
            Ks[kb + 2][lrow] = kv.z; Ks[kb + 3][lrow] = kv.w;
        }
        __syncthreads();
        #pragma unroll
        for (int k = 0; k < 16; k++) {
            float4 qa = *(const float4*)&Qs[k][ty * 8];
            float4 qb = *(const float4*)&Qs[k][ty * 8 + 4];
            float4 ka = *(const float4*)&Ks[k][tx * 8];
            float4 kb4 = *(const float4*)&Ks[k][tx * 8 + 4];
            float aq[8] = {qa.x, qa.y, qa.z, qa.w, qb.x, qb.y, qb.z, qb.w};
            float ak[8] = {ka.x, ka.y, ka.z, ka.w, kb4.x, kb4.y, kb4.z, kb4.w};
            #pragma unroll
            for (int i = 0; i < 8; i++)
                #pragma unroll
                for (int j = 0; j < 8; j++) acc[i][j] += aq[i] * ak[j];
        }
        __syncthreads();
    }
    float* Sb = S + (size_t)b * n * n;
    #pragma unroll
    for (int i = 0; i < 8; i++) {
        int r = r0 + ty * 8 + i;
        if (r < n) {
            #pragma unroll
            for (int j = 0; j < 8; j++) {
                int c = c0 + tx * 8 + j;
                if (c < n) Sb[(size_t)r * n + c] = acc[i][j];
            }
        }
    }
}

// ---------------------------------------------------------------------------
// 128-tile ABT: O[b,r,c] = sum_k A[b,r,k]*B[c,k]; B batch-shared; d-tail
// guarded scalar loads; cols [n,oLd) zero-filled.
// ---------------------------------------------------------------------------
__global__ void __launch_bounds__(256, 4)
k_abt128(const float* __restrict__ A, long long aBatch, int aLd,
         const float* __restrict__ B, int bLd,
         float* __restrict__ O, long long oBatch, int oLd, int n, int d) {
    __shared__ float Qs[16][132];
    __shared__ float Ks[16][132];
    int b  = blockIdx.z;
    int r0 = blockIdx.x * 128, c0 = blockIdx.y * 128;
    int tid = threadIdx.x;
    int tx = tid & 15, ty = tid >> 4;
    int lrow = tid >> 1;
    int lk   = (tid & 1) * 8;
    const float* Ar = A + (size_t)b * aBatch + (size_t)min(r0 + lrow, n - 1) * aLd;
    const float* Br = B + (size_t)min(c0 + lrow, n - 1) * bLd;

    float acc[8][8] = {};
    for (int kk = 0; kk < d; kk += 16) {
        #pragma unroll
        for (int h = 0; h < 2; h++) {
            int g = kk + lk + h * 4;
            float4 av, bv;
            if (g + 4 <= d) {
                av = *(const float4*)(Ar + g);
                bv = *(const float4*)(Br + g);
            } else {
                float ae[4], be[4];
                #pragma unroll
                for (int e = 0; e < 4; e++) {
                    int gg = g + e;
                    ae[e] = (gg < d) ? Ar[gg] : 0.f;
                    be[e] = (gg < d) ? Br[gg] : 0.f;
                }
                av = make_float4(ae[0], ae[1], ae[2], ae[3]);
                bv = make_float4(be[0], be[1], be[2], be[3]);
            }
            int kb = lk + h * 4;
            Qs[kb + 0][lrow] = av.x; Qs[kb + 1][lrow] = av.y;
            Qs[kb + 2][lrow] = av.z; Qs[kb + 3][lrow] = av.w;
            Ks[kb + 0][lrow] = bv.x; Ks[kb + 1][lrow] = bv.y;
            Ks[kb + 2][lrow] = bv.z; Ks[kb + 3][lrow] = bv.w;
        }
        __syncthreads();
        #pragma unroll
        for (int k = 0; k < 16; k++) {
            float4 qa = *(const float4*)&Qs[k][ty * 8];
            float4 qb = *(const float4*)&Qs[k][ty * 8 + 4];
            float4 ka = *(const float4*)&Ks[k][tx * 8];
            float4 kb4 = *(const float4*)&Ks[k][tx * 8 + 4];
            float aq[8] = {qa.x, qa.y, qa.z, qa.w, qb.x, qb.y, qb.z, qb.w};
            float ak[8] = {ka.x, ka.y, ka.z, ka.w, kb4.x, kb4.y, kb4.z, kb4.w};
            #pragma unroll
            for (int i = 0; i < 8; i++)
                #pragma unroll
                for (int j = 0; j < 8; j++) acc[i][j] += aq[i] * ak[j];
        }
        __syncthreads();
    }
    #pragma unroll
    for (int i = 0; i < 8; i++) {
        int r = r0 + ty * 8 + i;
        if (r < n) {
            #pragma unroll
            for (int j = 0; j < 8; j++) {
                int c = c0 + tx * 8 + j;
                if (c < oLd)
                    O[(size_t)b * oBatch + (size_t)r * oLd + c] = (c < n) ? acc[i][j] : 0.f;
            }
        }
    }
}

// ---------------------------------------------------------------------------
// f-branch scores split-K (n=58 fits a 64-tile).
// ---------------------------------------------------------------------------
__global__ void __launch_bounds__(256)
k_scores_sk(const float* __restrict__ Q, const float* __restrict__ K,
            float* __restrict__ SP, int n, int d, int kz_n, int chunk, int sQ) {
    __shared__ float Qs[16][68];
    __shared__ float Ks[16][68];
    int bz = blockIdx.z;
    int b  = bz / kz_n, kz = bz % kz_n;
    int k0 = kz * chunk, k1 = min(d, k0 + chunk);
    int r0 = blockIdx.x * 64, c0 = blockIdx.y * 64;
    int tx = threadIdx.x & 15, ty = threadIdx.x >> 4;
    int lrow = threadIdx.x >> 2;
    int lk   = (threadIdx.x & 3) * 4;
    const float* Qr = Q + (size_t)b * sQ + (size_t)min(r0 + lrow, n - 1) * d;
    const float* Kr = K + (size_t)b * sQ + (size_t)min(c0 + lrow, n - 1) * d;
    bool qok = (r0 + lrow) < n;
    bool kok = (c0 + lrow) < n;
    float acc[4][4] = {};

    for (int kk = k0; kk < k1; kk += 16) {
        #pragma unroll
        for (int u = 0; u < 4; u++) {
            int gk = kk + lk + u;
            bool gv = gk < k1;
            Qs[lk + u][lrow] = (qok && gv) ? Qr[gk] : 0.f;
            Ks[lk + u][lrow] = (kok && gv) ? Kr[gk] : 0.f;
        }
        __syncthreads();
        #pragma unroll
        for (int k = 0; k < 16; k++) {
            float4 q4 = *(const float4*)&Qs[k][ty * 4];
            float4 k4 = *(const float4*)&Ks[k][tx * 4];
            float aq[4] = {q4.x, q4.y, q4.z, q4.w};
            float ak[4] = {k4.x, k4.y, k4.z, k4.w};
            #pragma unroll
            for (int i = 0; i < 4; i++)
                #pragma unroll
                for (int j = 0; j < 4; j++) acc[i][j] += aq[i] * ak[j];
        }
        __syncthreads();
    }
    float* Sb = SP + (size_t)bz * n * n;
    #pragma unroll
    for (int i = 0; i < 4; i++) {
        int r = r0 + ty * 4 + i;
        #pragma unroll
        for (int j = 0; j < 4; j++) {
            int c = c0 + tx * 4 + j;
            if (r < n && c < n) Sb[(size_t)r * n + c] = acc[i][j];
        }
    }
}

// ---------------------------------------------------------------------------
// Small ABT (64-tile) for f/c gram transforms.
// ---------------------------------------------------------------------------
__global__ void __launch_bounds__(256)
k_abt(const float* __restrict__ A, long long aBatch, int aLd,
      const float* __restrict__ B, int bLd,
      float* __restrict__ O, long long oBatch, int oLd,
      int n, int d)
{
    __shared__ float Qs[16][68];
    __shared__ float Ks[16][68];
    int b  = blockIdx.z;
    int r0 = blockIdx.x * 64, c0 = blockIdx.y * 64;
    int tx = threadIdx.x & 15, ty = threadIdx.x >> 4;
    int lrow = threadIdx.x >> 2;
    int lk   = (threadIdx.x & 3) * 4;
    const float* Ar = A + (size_t)b * aBatch + (size_t)min(r0 + lrow, n - 1) * aLd;
    const float* Br = B + (size_t)min(c0 + lrow, n - 1) * bLd;
    bool aok = (r0 + lrow) < n;
    bool bok = (c0 + lrow) < n;
    float acc[4][4] = {};

    for (int kk = 0; kk < d; kk += 16) {
        #pragma unroll
        for (int u = 0; u < 4; u++) {
            int gk = kk + lk + u;
            bool gv = gk < d;
            Qs[lk + u][lrow] = (aok && gv) ? Ar[gk] : 0.f;
            Ks[lk + u][lrow] = (bok && gv) ? Br[gk] : 0.f;
        }
        __syncthreads();
        #pragma unroll
        for (int k = 0; k < 16; k++) {
            float4 q4 = *(const float4*)&Qs[k][ty * 4];
            float4 k4 = *(const float4*)&Ks[k][tx * 4];
            float aq[4] = {q4.x, q4.y, q4.z, q4.w};
            float ak[4] = {k4.x, k4.y, k4.z, k4.w};
            #pragma unroll
            for (int i = 0; i < 4; i++)
                #pragma unroll
                for (int j = 0; j < 4; j++) acc[i][j] += aq[i] * ak[j];
        }
        __syncthreads();
    }
    #pragma unroll
    for (int i = 0; i < 4; i++) {
        int r = r0 + ty * 4 + i;
        #pragma unroll
        for (int j = 0; j < 4; j++) {
            int c = c0 + tx * 4 + j;
            if (r < n && c < oLd)
                O[(size_t)b * oBatch + (size_t)r * oLd + c] = (c < n) ? acc[i][j] : 0.f;
        }
    }
}

// ---------------------------------------------------------------------------
// Row sums of Q and K views: sigma[b,r] = sum_l X[b*CFT + r*d + l]
// ---------------------------------------------------------------------------
__global__ void k_rowsum2(const float* __restrict__ Q, const float* __restrict__ K,
                          int n, int d, float* __restrict__ sQ, float* __restrict__ sK) {
    int b = blockIdx.x / n, r = blockIdx.x % n;
    const float* q = Q + (size_t)b * CFT + (size_t)r * d;
    const float* k = K + (size_t)b * CFT + (size_t)r * d;
    float s1 = 0.f, s2 = 0.f;
    for (int i = threadIdx.x; i < d; i += 256) { s1 += q[i]; s2 += k[i]; }
    __shared__ float red[2][256];
    red[0][threadIdx.x] = s1; red[1][threadIdx.x] = s2;
    __syncthreads();
    for (int s = 128; s > 0; s >>= 1) {
        if (threadIdx.x < s) {
            red[0][threadIdx.x] += red[0][threadIdx.x + s];
            red[1][threadIdx.x] += red[1][threadIdx.x + s];
        }
        __syncthreads();
    }
    if (threadIdx.x == 0) {
        sQ[(size_t)b * n + r] = red[0][0];
        sK[(size_t)b * n + r] = red[1][0];
    }
}

// ---------------------------------------------------------------------------
// u = Wq * sigmaQ ; v = Wk * sigmaK   (per batch)
// ---------------------------------------------------------------------------
__global__ void __launch_bounds__(256)
k_matvec2(const float* __restrict__ Wq, const float* __restrict__ Wk,
          const float* __restrict__ sQ, const float* __restrict__ sK,
          float* __restrict__ u, float* __restrict__ v, int n) {
    int b = blockIdx.x;
    __shared__ float sq[256], sk[256];
    for (int i = threadIdx.x; i < n; i += 256) {
        sq[i] = sQ[(size_t)b * n + i];
        sk[i] = sK[(size_t)b * n + i];
    }
    __syncthreads();
    for (int r = threadIdx.x; r < n; r += 256) {
        float a = 0.f, bb = 0.f;
        for (int m = 0; m < n; m++) {
            a  += Wq[(size_t)r * n + m] * sq[m];
            bb += Wk[(size_t)r * n + m] * sk[m];
        }
        u[(size_t)b * n + r] = a;
        v[(size_t)b * n + r] = bb;
    }
}

// ---------------------------------------------------------------------------
// Combine split-K partials.
// ---------------------------------------------------------------------------
__global__ void k_scombine(const float* __restrict__ SP, float* __restrict__ S,
                           int n, int kz_n) {
    int idx = blockIdx.x * 256 + threadIdx.x;
    int nn = n * n;
    if (idx >= Bn * nn) return;
    int b = idx / nn, rc = idx % nn;
    float s = 0.f;
    for (int kz = 0; kz < kz_n; kz++) s += SP[((size_t)b * kz_n + kz) * nn + rc];
    S[(size_t)b * nn + rc] = s;
}

// ---------------------------------------------------------------------------
// c-branch gram: 8x8 over d=FT, 8 l-chunks of partials.
// ---------------------------------------------------------------------------
#define C_LZ 8
__global__ void k_gram8(const float* __restrict__ Q, const float* __restrict__ K,
                        float* __restrict__ SP) {
    int b  = blockIdx.x / C_LZ;
    int lz = blockIdx.x % C_LZ;
    int g  = threadIdx.x >> 6;
    int p  = threadIdx.x & 63;
    int r  = p >> 3, c = p & 7;
    const float* Qb = Q + (size_t)b * CFT + (size_t)r * FT;
    const float* Kb = K + (size_t)b * CFT + (size_t)c * FT;
    int chunk = (FT + C_LZ - 1) / C_LZ;
    int l0 = lz * chunk, l1 = min(FT, l0 + chunk);
    float acc = 0.f;
    for (int l = l0 + g; l < l1; l += 4) acc += Qb[l] * Kb[l];
    __shared__ float red[256];
    red[threadIdx.x] = acc;
    __syncthreads();
    if (threadIdx.x < 64) {
        float s = red[p] + red[64 + p] + red[128 + p] + red[192 + p];
        SP[(size_t)blockIdx.x * 64 + p] = s;
    }
}

// ---------------------------------------------------------------------------
// Dual column softmax: Sacc = softmax(S1) + softmax(S2 + rank1).
// ---------------------------------------------------------------------------
__global__ void __launch_bounds__(256)
k_softmax2(const float* __restrict__ S1, long long b1, int ld1,
           const float* __restrict__ S2, long long b2, int ld2,
           float* __restrict__ Sacc, long long aB,
           int n, int cb, float scale,
           const float* __restrict__ bq, const float* __restrict__ u,
           const float* __restrict__ vv, const float* __restrict__ bk, float dlen) {
    __shared__ float redA[4][64];
    __shared__ float redB[4][64];
    int b  = blockIdx.x / cb;
    int tc = threadIdx.x & 63;
    int g  = threadIdx.x >> 6;
    int c  = (blockIdx.x % cb) * 64 + tc;
    bool act = c < n;
    const float* A1 = S1 + (size_t)b * b1;
    const float* A2 = S2 + (size_t)b * b2;
    const float* ub = u + (size_t)b * n;
    float alpha = 0.f, beta = 0.f;
    if (act) {
        beta  = bk[c];
        alpha = vv[(size_t)b * n + c] + dlen * beta;
    }
    auto V1 = [&](int r) { return A1[(size_t)r * ld1 + c]; };
    auto V2 = [&](int r) { return A2[(size_t)r * ld2 + c] + bq[r] * alpha + ub[r] * beta; };

    float m1 = -1e30f, m2 = -1e30f;
    if (act) for (int r = g; r < n; r += 4) {
        m1 = fmaxf(m1, V1(r)); m2 = fmaxf(m2, V2(r));
    }
    redA[g][tc] = m1; redB[g][tc] = m2;
    __syncthreads();
    m1 = fmaxf(fmaxf(redA[0][tc], redA[1][tc]), fmaxf(redA[2][tc], redA[3][tc]));
    m2 = fmaxf(fmaxf(redB[0][tc], redB[1][tc]), fmaxf(redB[2][tc], redB[3][tc]));
    __syncthreads();

    float s1 = 0.f, s2 = 0.f;
    if (act) for (int r = g; r < n; r += 4) {
        s1 += __expf((V1(r) - m1) * scale);
        s2 += __expf((V2(r) - m2) * scale);
    }
    redA[g][tc] = s1; redB[g][tc] = s2;
    __syncthreads();
    float i1 = 1.f / (redA[0][tc] + redA[1][tc] + redA[2][tc] + redA[3][tc]);
    float i2 = 1.f / (redB[0][tc] + redB[1][tc] + redB[2][tc] + redB[3][tc]);
    if (act) {
        float* Ab = Sacc + (size_t)b * aB;
        for (int r = g; r < n; r += 4) {
            Ab[(size_t)r * n + c] = __expf((V1(r) - m1) * scale) * i1
                                  + __expf((V2(r) - m2) * scale) * i2;
        }
    }
}

// ---------------------------------------------------------------------------
// Column softmax (single matrix), optional rank-1, Sacc accumulate or
// in-place destructive.
// ---------------------------------------------------------------------------
__global__ void __launch_bounds__(256)
k_softmax(float* __restrict__ S, long long sBatch, int ldS,
          float* __restrict__ Sacc, long long aBatch,
          int n, int cb, float scale, int first,
          const float* __restrict__ bq, const float* __restrict__ u,
          const float* __restrict__ vv, const float* __restrict__ bk,
          float dlen) {
    __shared__ float red[4][64];
    int b  = blockIdx.x / cb;
    int tc = threadIdx.x & 63;
    int g  = threadIdx.x >> 6;
    int c  = (blockIdx.x % cb) * 64 + tc;
    bool act = c < n;
    float* Sb = S + (size_t)b * sBatch;
    bool r1 = (bq != nullptr);
    const float* ub = r1 ? u + (size_t)b * n : nullptr;
    float alpha = 0.f, beta = 0.f;
    if (r1 && act) {
        beta  = bk[c];
        alpha = vv[(size_t)b * n + c] + dlen * beta;
    }
    auto VAL = [&](int r) {
        float s = Sb[(size_t)r * ldS + c];
        if (r1) s += bq[r] * alpha + ub[r] * beta;
        return s;
    };

    float mx = -1e30f;
    if (act) for (int r = g; r < n; r += 4) mx = fmaxf(mx, VAL(r));
    red[g][tc] = mx;
    __syncthreads();
    mx = fmaxf(fmaxf(red[0][tc], red[1][tc]), fmaxf(red[2][tc], red[3][tc]));
    __syncthreads();

    float sum = 0.f;
    if (act) {
        if (Sacc) {
            for (int r = g; r < n; r += 4) sum += __expf((VAL(r) - mx) * scale);
        } else {
            for (int r = g; r < n; r += 4) {
                float e = __expf((VAL(r) - mx) * scale);
                Sb[(size_t)r * ldS + c] = e;
                sum += e;
            }
        }
    }
    red[g][tc] = sum;
    __syncthreads();
    float inv = 1.f / (red[0][tc] + red[1][tc] + red[2][tc] + red[3][tc]);
    if (act) {
        if (Sacc) {
            float* Ab = Sacc + (size_t)b * aBatch;
            for (int r = g; r < n; r += 4) {
                float e = __expf((VAL(r) - mx) * scale) * inv;
                size_t o = (size_t)r * n + c;
                Ab[o] = first ? e : (Ab[o] + e);
            }
        } else {
            for (int r = g; r < n; r += 4) Sb[(size_t)r * ldS + c] *= inv;
        }
    }
}

// ---------------------------------------------------------------------------
// xr spatial mean per (b, rc)
// ---------------------------------------------------------------------------
__global__ void k_mean(const float* __restrict__ inp, const float* __restrict__ w_res,
                       const float* __restrict__ b_res, const float* __restrict__ bn_gamma,
                       const float* __restrict__ bn_beta, const float* __restrict__ bn_mean,
                       const float* __restrict__ bn_var, float* __restrict__ meanbuf) {
    int b  = blockIdx.x / RCn;
    int rc = blockIdx.x % RCn;
    float w[9];
    #pragma unroll
    for (int i = 0; i < 9; i++) w[i] = w_res[rc * 9 + i];
    float g    = bn_gamma[rc] * rsqrtf(bn_var[rc] + 1e-5f);
    float bias = (b_res[rc] - bn_mean[rc]) * g + bn_beta[rc];
    const float* ib = inp + (size_t)b * IH * IW;

    float sum = 0.f;
    for (int idx = threadIdx.x; idx < FT; idx += 256) {
        int f = idx / Tn, t = idx % Tn;
        const float* p = ib + f * IW + t;
        float v = w[0]*p[0]     + w[1]*p[1]     + w[2]*p[2]
                + w[3]*p[IW]    + w[4]*p[IW+1]  + w[5]*p[IW+2]
                + w[6]*p[2*IW]  + w[7]*p[2*IW+1]+ w[8]*p[2*IW+2];
        sum += v * g + bias;
    }
    __shared__ float red[256];
    red[threadIdx.x] = sum;
    __syncthreads();
    for (int s = 128; s > 0; s >>= 1) {
        if (threadIdx.x < s) red[threadIdx.x] += red[threadIdx.x + s];
        __syncthreads();
    }
    if (threadIdx.x == 0) meanbuf[b * RCn + rc] = red[0] / (float)FT;
}

// ---------------------------------------------------------------------------
// dyReLU coefficient MLP
// ---------------------------------------------------------------------------
__global__ void k_coef(const float* __restrict__ meanbuf, const float* __restrict__ w1,
                       const float* __restrict__ b1, const float* __restrict__ w2,
                       const float* __restrict__ b2, float* __restrict__ coef) {
    int b = blockIdx.x;
    int k = threadIdx.x;
    if (k >= 4 * RCn) return;
    const float* th = meanbuf + b * RCn;
    float h[6];
    #pragma unroll
    for (int j = 0; j < 6; j++) {
        float s = b1[j];
        #pragma unroll
        for (int c = 0; c < RCn; c++) s += th[c] * w1[j * RCn + c];
        h[j] = fmaxf(s, 0.f);
    }
    float s = b2[k];
    #pragma unroll
    for (int j = 0; j < 6; j++) s += h[j] * w2[k * 6 + j];
    float g2 = 2.f / (1.f + __expf(-s)) - 1.f;
    const float lam[4] = {1.f, 1.f, 0.5f, 0.5f};
    const float ini[4] = {1.f, 0.f, 0.f, 0.f};
    coef[b * 96 + k] = g2 * lam[k & 3] + ini[k & 3];
}

// ---------------------------------------------------------------------------
// recompute conv+BN, apply dyReLU, out += xr. Grid (Fn, RCn, Bn), zero div/mod.
// ---------------------------------------------------------------------------
__global__ void __launch_bounds__(256)
k_xr_add(const float* __restrict__ inp, const float* __restrict__ w_res,
         const float* __restrict__ b_res, const float* __restrict__ bn_gamma,
         const float* __restrict__ bn_beta, const float* __restrict__ bn_mean,
         const float* __restrict__ bn_var, const float* __restrict__ coef,
         float* __restrict__ out) {
    int t  = threadIdx.x;
    if (t >= Tn) return;
    int f  = blockIdx.x;
    int rc = blockIdx.y;
    int b  = blockIdx.z;

    const float* wp = w_res + rc * 9;
    float g    = bn_gamma[rc] * rsqrtf(bn_var[rc] + 1e-5f);
    float bias = (b_res[rc] - bn_mean[rc]) * g + bn_beta[rc];
    const float* cf = coef + ((size_t)b * RCn + rc) * 4;
    float c0 = cf[0], c1 = cf[1], c2 = cf[2], c3 = cf[3];

    const float* p = inp + (size_t)b * IH * IW + f * IW + t;
    float v = wp[0]*p[0]    + wp[1]*p[1]      + wp[2]*p[2]
            + wp[3]*p[IW]   + wp[4]*p[IW+1]   + wp[5]*p[IW+2]
            + wp[6]*p[2*IW] + wp[7]*p[2*IW+1] + wp[8]*p[2*IW+2];
    float xv = v * g + bias;
    float r = fmaxf(xv * c0 + c2, xv * c1 + c3);
    out[(size_t)b * OUTB + (size_t)rc * FT + (size_t)f * Tn + t] += r;
}

// ---------------------------------------------------------------------------
extern "C" void kernel_launch(void* const* d_in, const int* in_sizes, int n_in,
                              void* d_out, int out_size, void* d_ws, size_t ws_size,
                              hipStream_t stream) {
    const float* x        = (const float*)d_in[0];
    const float* inp      = (const float*)d_in[1];
    const float* w_diff   = (const float*)d_in[2];
    const float* b_diff   = (const float*)d_in[3];
    const float* w_res    = (const float*)d_in[4];
    const float* b_res    = (const float*)d_in[5];
    const float* bn_gamma = (const float*)d_in[6];
    const float* bn_beta  = (const float*)d_in[7];
    const float* bn_mean  = (const float*)d_in[8];
    const float* bn_var   = (const float*)d_in[9];
    const float* dy_w1    = (const float*)d_in[10];
    const float* dy_b1    = (const float*)d_in[11];
    const float* dy_w2    = (const float*)d_in[12];
    const float* dy_b2    = (const float*)d_in[13];
    const float* wq       = (const float*)d_in[14];
    const float* bq       = (const float*)d_in[15];
    const float* wk       = (const float*)d_in[16];
    const float* bk       = (const float*)d_in[17];
    const float* fq0_w    = (const float*)d_in[18];
    const float* fq0_b    = (const float*)d_in[19];
    const float* fk0_w    = (const float*)d_in[20];
    const float* fk0_b    = (const float*)d_in[21];
    const float* cq0_w    = (const float*)d_in[22];
    const float* cq0_b    = (const float*)d_in[23];
    const float* ck0_w    = (const float*)d_in[24];
    const float* ck0_b    = (const float*)d_in[25];
    const float* tq0_w    = (const float*)d_in[26];
    const float* tq0_b    = (const float*)d_in[27];
    const float* tk0_w    = (const float*)d_in[28];
    const float* tk0_b    = (const float*)d_in[29];
    const float* tq1_w    = (const float*)d_in[30];
    const float* tq1_b    = (const float*)d_in[31];
    const float* tk1_w    = (const float*)d_in[32];
    const float* tk1_b    = (const float*)d_in[33];

    float* out = (float*)d_out;
    float* ws  = (float*)d_ws;

    const size_t NB  = (size_t)Bn * CFT;
    const size_t SNN = (size_t)Bn * Tn * Tn;          // 7,936,128 floats
    float* V       = ws;
    float* Q       = ws + NB;
    float* K       = ws + 2 * NB;
    float* Qp      = ws + 3 * NB;
    float* Kp      = ws + 4 * NB;
    float* S       = ws + 5 * NB;                     // SNN floats
    float* meanbuf = S + SNN;
    float* coef    = meanbuf + 3072;
    float* SaccT   = coef + 12288;                    // SNN, only if fuseT
    // scratch inside existing regions (per-branch lifetimes, sequential):
    float* T2f   = S + 1000000;      // f/c: T2 (ld 60 / ld 8)
    float* S2f   = S + 2000000;      // f/c: S2
    float* SaccF = S + 3000000;      // f P-sum (430,592)
    float* SaccC = S + 3500000;      // c P-sum (8,192)
    float* SPp   = S + 4000000;      // split-K / gram partials (3.44M)
    // t-branch re-homing: Q,K die after the s2 convs + rowsum2, so T2 lives
    // in the Q region and S2 in the K region; conv outputs take Qp/Kp.
    float* T2t   = Q;                // 249*252*128 = 8.03M <= NB
    float* S2t   = K;
    float* sg    = Kp + 9000000;     // sigma/u/v block (Kp tail; conv-k uses <7.4M)
    float *sQt = sg,          *sKt = sg + 32000,  *ut = sg + 64000,  *vt = sg + 96000;
    float *sQf = sg + 128000, *sKf = sg + 136000, *uf = sg + 144000, *vf = sg + 152000;
    float *sQc = sg + 160000, *sKc = sg + 161024, *uc = sg + 162048, *vc = sg + 163072;
    bool fuseT = ws_size >= (5 * NB + 2 * SNN + 15360) * sizeof(float);

    k_differ_qk<<<dim3(1, Fn, Bn), dim3(256), 0, stream>>>(
        x, w_diff, b_diff, wq, bq, wk, bk, V, Q, K);

    const float scF   = 1.0f / sqrtf(1992.f);
    const float scC   = 1.0f / sqrtf((float)FT);
    const float sc464 = 1.0f / sqrtf(464.f);
    const float sc232 = 1.0f / sqrtf(232.f);

    // ======== f branch (n=58, d=1992, sec=0) — gram transform ========
    {
        dim3 g1(1, 1, Bn * 8);
        k_scores_sk<<<g1, dim3(256), 0, stream>>>(Q, K, SPp, Fn, 1992, 8, 256, CFT);
        k_scombine<<<dim3((Bn * Fn * Fn + 255) / 256), dim3(256), 0, stream>>>(SPp, S, Fn, 8);
        k_rowsum2<<<dim3(Bn * Fn), dim3(256), 0, stream>>>(Q, K, Fn, 1992, sQf, sKf);
        k_matvec2<<<dim3(Bn), dim3(256), 0, stream>>>(fq0_w, fk0_w, sQf, sKf, uf, vf, Fn);
        k_abt<<<dim3(1, 1, Bn), dim3(256), 0, stream>>>(S, 3364, Fn, fk0_w, Fn,
                                                        T2f, 3480, 60, Fn, Fn);
        k_gemm<Fn, 8, 4, 4><<<dim3(Bn * 2), dim3(256), 0, stream>>>(
            fq0_w, 0, Fn, nullptr, T2f, 3480, 60, S2f, 3480, 0, 1, 2);
        k_softmax2<<<dim3(Bn), dim3(256), 0, stream>>>(
            S, 3364, Fn, S2f, 3480, 60, SaccF, 3364, Fn, 1, scF,
            fq0_b, uf, vf, fk0_b, 1992.f);
        k_gemm<Fn, 15, 2, 4><<<dim3(Bn * 8), dim3(256), 0, stream>>>(
            SaccF, 3364, Fn, nullptr, V, CFT, 1992, out, OUTB, 0, 4, 2);
    }

    // ======== c branch (n=8, d=FT, sec=1) — gram transform ========
    {
        k_gram8<<<dim3(Bn * C_LZ), dim3(256), 0, stream>>>(Q, K, SPp);
        k_scombine<<<dim3((Bn * 64 + 255) / 256), dim3(256), 0, stream>>>(SPp, S, Cn, C_LZ);
        k_rowsum2<<<dim3(Bn * Cn), dim3(256), 0, stream>>>(Q, K, Cn, FT, sQc, sKc);
        k_matvec2<<<dim3(Bn), dim3(256), 0, stream>>>(cq0_w, ck0_w, sQc, sKc, uc, vc, Cn);
        k_abt<<<dim3(1, 1, Bn), dim3(256), 0, stream>>>(S, 64, Cn, ck0_w, Cn,
                                                        T2f, 64, 8, Cn, Cn);
        k_gemm<Cn, 8, 1, 2><<<dim3(Bn), dim3(256), 0, stream>>>(
            cq0_w, 0, Cn, nullptr, T2f, 64, 8, S2f, 64, 0, 1, 1);
        k_softmax2<<<dim3(Bn), dim3(256), 0, stream>>>(
            S, 64, Cn, S2f, 64, 8, SaccC, 64, Cn, 1, scC,
            cq0_b, uc, vc, ck0_b, (float)FT);
        k_gemm<Cn, 8, 1, 2><<<dim3(Bn * 29), dim3(256), 0, stream>>>(
            SaccC, 64, Cn, nullptr, V, CFT, FT, out + CFT, OUTB, 0, 29, 1);
    }

    // ======== t branch (n=249, dv=464, sec=2) ========
    {
        // 1) round-0 gram + rowsums (streams Q,K -> L3-warm)
        k_scores128<<<dim3(2, 2, Bn), dim3(256), 0, stream>>>(Q, K, S, Tn, 464, CFT);
        k_rowsum2<<<dim3(Bn * Tn), dim3(256), 0, stream>>>(Q, K, Tn, 464, sQt, sKt);
        // 2) stride-2 convs while Q/K are warm (R7 lesson). Outputs -> Qp/Kp.
        k_gemm_s2<Tn, 4><<<dim3(Bn * 16), dim3(256), 0, stream>>>(
            tq1_w, tq1_b, Q, CFT, 464, 232, Qp, (long long)Tn * 232, 16);
        k_gemm_s2<Tn, 4><<<dim3(Bn * 16), dim3(256), 0, stream>>>(
            tk1_w, tk1_b, K, CFT, 464, 232, Kp, (long long)Tn * 232, 16);
        // 3) gram transform: Q,K regions now dead -> host T2/S2 there.
        k_matvec2<<<dim3(Bn), dim3(256), 0, stream>>>(tq0_w, tk0_w, sQt, sKt, ut, vt, Tn);
        k_abt128<<<dim3(2, 2, Bn), dim3(256), 0, stream>>>(S, 62001, Tn, tk0_w, Tn,
                                                           T2t, 62748, 252, Tn, Tn);
        k_gemm<Tn, 8, 4, 4><<<dim3(Bn * 8), dim3(256), 0, stream>>>(
            tq0_w, 0, Tn, nullptr, T2t, 62748, 252, S2t, 62748, 0, 1, 8);
        if (fuseT) {
            k_softmax2<<<dim3(Bn * 4), dim3(256), 0, stream>>>(
                S, 62001, Tn, S2t, 62748, 252, SaccT, 62001, Tn, 4, sc464,
                tq0_b, ut, vt, tk0_b, 464.f);
            k_scores128<<<dim3(2, 2, Bn), dim3(256), 0, stream>>>(Qp, Kp, S, Tn, 232, Tn * 232);
            k_softmax<<<dim3(Bn * 4), dim3(256), 0, stream>>>(
                S, 62001, Tn, SaccT, 62001, Tn, 4, sc232, 0,
                nullptr, nullptr, nullptr, nullptr, 0.f);
            k_gemm<Tn, 16, 2, 4><<<dim3(Bn * 8), dim3(256), 0, stream>>>(
                SaccT, 62001, Tn, nullptr, V, CFT, 464, out + 2 * CFT, OUTB, 0, 1, 8);
        } else {
            k_softmax<<<dim3(Bn * 4), dim3(256), 0, stream>>>(
                S, 62001, Tn, nullptr, 0, Tn, 4, sc464, 0,
                nullptr, nullptr, nullptr, nullptr, 0.f);
            k_gemm<Tn, 16, 2, 4><<<dim3(Bn * 8), dim3(256), 0, stream>>>(
                S, 62001, Tn, nullptr, V, CFT, 464, out + 2 * CFT, OUTB, 0, 1, 8);
            k_softmax<<<dim3(Bn * 4), dim3(256), 0, stream>>>(
                S2t, 62748, 252, nullptr, 0, Tn, 4, sc464, 0,
                tq0_b, ut, vt, tk0_b, 464.f);
            k_gemm<Tn, 16, 2, 4><<<dim3(Bn * 8), dim3(256), 0, stream>>>(
                S2t, 62748, 252, nullptr, V, CFT, 464, out + 2 * CFT, OUTB, 1, 1, 8);
            k_scores128<<<dim3(2, 2, Bn), dim3(256), 0, stream>>>(Qp, Kp, S, Tn, 232, Tn * 232);
            k_softmax<<<dim3(Bn * 4), dim3(256), 0, stream>>>(
                S, 62001, Tn, nullptr, 0, Tn, 4, sc232, 0,
                nullptr, nullptr, nullptr, nullptr, 0.f);
            k_gemm<Tn, 16, 2, 4><<<dim3(Bn * 8), dim3(256), 0, stream>>>(
                S, 62001, Tn, nullptr, V, CFT, 464, out + 2 * CFT, OUTB, 1, 1, 8);
        }
    }

    // ---- xr residual path
    k_mean<<<dim3(Bn * RCn), dim3(256), 0, stream>>>(
        inp, w_res, b_res, bn_gamma, bn_beta, bn_mean, bn_var, meanbuf);
    k_coef<<<dim3(Bn), dim3(128), 0, stream>>>(meanbuf, dy_w1, dy_b1, dy_w2, dy_b2, coef);
    k_xr_add<<<dim3(Fn, RCn, Bn), dim3(256), 0, stream>>>(
        inp, w_res, b_res, bn_gamma, bn_beta, bn_mean, bn_var, coef, out);
}

// Round 15
// 1945.980 us; speedup vs baseline: 1.0252x; 1.0252x over previous
//
#include <hip/hip_runtime.h>
#include <cmath>

#define Bn   128
#define Cn   8
#define Fn   58
#define Tn   249
#define RCn  24
#define FT   14442      // Fn*Tn
#define CFT  115536     // Cn*Fn*Tn
#define OUTB 346608     // 3*CFT per-batch output
#define IH   60
#define IW   251

// ---------------------------------------------------------------------------
// differ = concat([x[...,:1], W_diff@x + b_diff (shift) - x[...,:-1]], -1)
// Q = wq@differ + bq ; K = wk@differ + bk ; V = differ
// ---------------------------------------------------------------------------
__global__ void __launch_bounds__(256)
k_differ_qk(const float* __restrict__ x,
            const float* __restrict__ w_diff, const float* __restrict__ b_diff,
            const float* __restrict__ wq, const float* __restrict__ bq,
            const float* __restrict__ wk, const float* __restrict__ bk,
            float* __restrict__ V, float* __restrict__ Q, float* __restrict__ K) {
    int t = threadIdx.x;
    if (t >= Tn) return;
    int f  = blockIdx.y;
    int b  = blockIdx.z;
    int ft = f * Tn + t;
    const float* xb = x + (size_t)b * CFT + ft;

    float xv[Cn], d[Cn];
    #pragma unroll
    for (int c = 0; c < Cn; c++) xv[c] = xb[c * FT];

    if (t == 0) {
        #pragma unroll
        for (int c = 0; c < Cn; c++) d[c] = xv[c];
    } else {
        #pragma unroll
        for (int o = 0; o < Cn; o++) {
            float s = b_diff[o];
            #pragma unroll
            for (int c = 0; c < Cn; c++) s += w_diff[o * Cn + c] * xv[c];
            d[o] = s - xb[o * FT - 1];
        }
    }

    float* Vb = V + (size_t)b * CFT + ft;
    float* Qb = Q + (size_t)b * CFT + ft;
    float* Kb = K + (size_t)b * CFT + ft;
    #pragma unroll
    for (int o = 0; o < Cn; o++) {
        Vb[o * FT] = d[o];
        float q = bq[o], k = bk[o];
        #pragma unroll
        for (int c = 0; c < Cn; c++) { q += wq[o * Cn + c] * d[c]; k += wk[o * Cn + c] * d[c]; }
        Qb[o * FT] = q;
        Kb[o * FT] = k;
    }
}

// ---------------------------------------------------------------------------
// Column-owner register GEMM (v7 body).
// ---------------------------------------------------------------------------
template<int AN, int RG, int GW, int VL>
__global__ void __launch_bounds__(256, 4)
k_gemm(const float* __restrict__ A, long long aStride, int aLd,
       const float* __restrict__ bias,
       const float* __restrict__ V, long long vStride, int dv,
       float* __restrict__ out, long long oStride, int add,
       int gx, int gy)
{
    constexpr int TPG = 256 / GW;
    constexpr int RGA = (RG + 3) & ~3;
    constexpr int RGP = GW * RGA + 4;    // 16B-aligned row stride
    __shared__ float As[64][RGP];

    int nblk = gridDim.x;
    int bid  = blockIdx.x;
    if ((nblk & 7) == 0) {               // bijective XCD swizzle
        int cpx = nblk >> 3;
        bid = (bid & 7) * cpx + (bid >> 3);
    }
    int gxy = gx * gy;
    int b   = bid / gxy;
    int rem = bid - b * gxy;
    int jb  = (rem / gx) * (GW * RG);
    int g   = threadIdx.x / TPG;         // wave-aligned group id
    int cl  = threadIdx.x % TPG;
    int j0  = jb + g * RG;
    int l   = (rem % gx) * (TPG * VL) + cl * VL;
    bool act = (l + VL <= dv);

    const float* Ab = A + (size_t)b * aStride;
    const float* Vb = V + (size_t)b * vStride + l;

    float acc[RG][VL];
    #pragma unroll
    for (int j = 0; j < RG; j++)
        #pragma unroll
        for (int e = 0; e < VL; e++) acc[j][e] = 0.f;

    for (int m0 = 0; m0 < AN; m0 += 64) {
        int mc = min(64, AN - m0);
        for (int idx = threadIdx.x; idx < GW * RG * 64; idx += 256) {
            int j = idx >> 6, mi = idx & 63;
            float w = 0.f;
            if (jb + j < AN && mi < mc) w = Ab[(size_t)(jb + j) * aLd + m0 + mi];
            As[mi][(j / RG) * RGA + (j % RG)] = w;
        }
        __syncthreads();
        if (act) {
            const float* Vp = Vb + (size_t)m0 * dv;
            auto LD = [&](int i) -> float4 {
                const float* p = Vp + (size_t)i * dv;     // affine
                if constexpr (VL == 4) {
                    return *(const float4*)p;
                } else {
                    float2 t = *(const float2*)p;
                    return make_float4(t.x, t.y, 0.f, 0.f);
                }
            };
            auto FMA = [&](int mm, float4 x) {
                const float* w = &As[mm][g * RGA];
                #pragma unroll
                for (int j = 0; j < RG; j++) {
                    float wv = w[j];
                    acc[j][0] += wv * x.x;
                    if constexpr (VL >= 2) acc[j][1] += wv * x.y;
                    if constexpr (VL >= 4) {
                        acc[j][2] += wv * x.z;
                        acc[j][3] += wv * x.w;
                    }
                }
            };
            float4 p0 = LD(0), p1 = LD(1), p2 = LD(2), p3 = LD(3);
            int mm = 0;
            for (; mm + 4 <= mc; mm += 4) {
                FMA(mm + 0, p0); p0 = LD(mm + 4);
                FMA(mm + 1, p1); p1 = LD(mm + 5);
                FMA(mm + 2, p2); p2 = LD(mm + 6);
                FMA(mm + 3, p3); p3 = LD(mm + 7);
            }
            if (mm     < mc) FMA(mm,     p0);
            if (mm + 1 < mc) FMA(mm + 1, p1);
            if (mm + 2 < mc) FMA(mm + 2, p2);
        }
        __syncthreads();
    }

    if (!act) return;
    float* ob = out + (size_t)b * oStride + l;
    #pragma unroll
    for (int j = 0; j < RG; j++) {
        if (j0 + j < AN) {
            float bv = bias ? bias[j0 + j] : 0.f;
            float* op = ob + (size_t)(j0 + j) * dv;
            if (add) {
                #pragma unroll
                for (int e = 0; e < VL; e++) op[e] += acc[j][e] + bv;
            } else {
                if constexpr (VL == 4) {
                    *(float4*)op = make_float4(acc[j][0] + bv, acc[j][1] + bv,
                                               acc[j][2] + bv, acc[j][3] + bv);
                } else {
                    *(float2*)op = make_float2(acc[j][0] + bv, acc[j][1] + bv);
                }
            }
        }
    }
}

// ---------------------------------------------------------------------------
// Stride-2 conv: EXACT R11/R13-measured kernel (185us @ warm X; VGPR=48,
// occupancy 43%). FROZEN — all four perturbations measured worse:
//   R10 RGW=8+dual-path: acc spill (WRITE 1.47GB)
//   R12 dual-path alone: partial spill (WRITE 82MB)
//   R14 unclamped single-path: -2.5us in-kernel but VGPR 48->60,
//       occupancy 43->37.5%, total +27us (bench reproducibility ±0.05us)
// The clamped single-path RGW=4 body is the measured global optimum.
// ---------------------------------------------------------------------------
template<int AN, int RGW>
__global__ void __launch_bounds__(256, 4)
k_gemm_s2(const float* __restrict__ W, const float* __restrict__ bias,
          const float* __restrict__ X, long long xStride, int d_in, int d_out,
          float* __restrict__ out, long long oStride, int gy)
{
    constexpr int BR = 4 * RGW;
    __shared__ float Ws[64][2 * BR + 4];

    int nblk = gridDim.x;
    int bid  = blockIdx.x;
    if ((nblk & 7) == 0) {
        int cpx = nblk >> 3;
        bid = (bid & 7) * cpx + (bid >> 3);
    }
    int b    = bid / gy;
    int jb   = (bid % gy) * BR;
    int w    = threadIdx.x >> 6;
    int lane = threadIdx.x & 63;
    int j0   = jb + w * RGW;
    int l4   = lane * 4;
    bool act = l4 < d_out;                   // d_out=232 -> lanes 0..57

    const float* Xb = X + (size_t)b * xStride + 2 * l4;

    float acc[RGW][4];
    #pragma unroll
    for (int j = 0; j < RGW; j++)
        #pragma unroll
        for (int e = 0; e < 4; e++) acc[j][e] = 0.f;

    for (int m0 = 0; m0 < AN; m0 += 64) {
        int mc = min(64, AN - m0);
        for (int idx = threadIdx.x; idx < 2 * BR * 64; idx += 256) {
            int mi = idx & 63, rest = idx >> 6;
            int rj = rest >> 1, tap = rest & 1;
            float wv = 0.f;
            if (jb + rj < AN && mi < mc)
                wv = W[((size_t)(jb + rj) * AN + m0 + mi) * 2 + tap];
            Ws[mi][2 * rj + tap] = wv;
        }
        __syncthreads();
        if (act) {
            const float* Xp = Xb + (size_t)m0 * d_in;
            auto FMAS = [&](int mm, float4 x0, float4 x1) {
                const float* wrow = &Ws[mm][2 * (w * RGW)];
                #pragma unroll
                for (int j = 0; j < RGW; j++) {
                    float w0 = wrow[2 * j], w1 = wrow[2 * j + 1];
                    acc[j][0] += w0 * x0.x + w1 * x0.y;
                    acc[j][1] += w0 * x0.z + w1 * x0.w;
                    acc[j][2] += w0 * x1.x + w1 * x1.y;
                    acc[j][3] += w0 * x1.z + w1 * x1.w;
                }
            };
            auto LDP = [&](int i, float4& a, float4& bb) {
                const float* p = Xp + (size_t)min(i, mc - 1) * d_in;
                a = *(const float4*)p; bb = *(const float4*)(p + 4);
            };
            float4 a0, b0, a1, b1, a2, b2, a3, b3;
            LDP(0, a0, b0); LDP(1, a1, b1); LDP(2, a2, b2); LDP(3, a3, b3);
            int mm = 0;
            for (; mm + 4 <= mc; mm += 4) {
                FMAS(mm + 0, a0, b0); LDP(mm + 4, a0, b0);
                FMAS(mm + 1, a1, b1); LDP(mm + 5, a1, b1);
                FMAS(mm + 2, a2, b2); LDP(mm + 6, a2, b2);
                FMAS(mm + 3, a3, b3); LDP(mm + 7, a3, b3);
            }
            if (mm     < mc) FMAS(mm,     a0, b0);
            if (mm + 1 < mc) FMAS(mm + 1, a1, b1);
            if (mm + 2 < mc) FMAS(mm + 2, a2, b2);
        }
        __syncthreads();
    }

    if (!act) return;
    float* ob = out + (size_t)b * oStride + l4;
    #pragma unroll
    for (int j = 0; j < RGW; j++) {
        if (j0 + j < AN) {
            float bv = bias[j0 + j];
            *(float4*)(ob + (size_t)(j0 + j) * d_out) =
                make_float4(acc[j][0] + bv, acc[j][1] + bv,
                            acc[j][2] + bv, acc[j][3] + bv);
        }
    }
}

// ---------------------------------------------------------------------------
// t-branch scores: 128x128 tile, 8x8 per thread.
// ---------------------------------------------------------------------------
__global__ void __launch_bounds__(256, 4)
k_scores128(const float* __restrict__ Q, const float* __restrict__ K,
            float* __restrict__ S, int n, int d, int sQ) {
    __shared__ float Qs[16][132];
    __shared__ float Ks[16][132];
    int b  = blockIdx.z;
    int r0 = blockIdx.x * 128, c0 = blockIdx.y * 128;
    int tid = threadIdx.x;
    int tx = tid & 15, ty = tid >> 4;
    int lrow = tid >> 1;
    int lk   = (tid & 1) * 8;
    const float* Qr = Q + (size_t)b * sQ + (size_t)min(r0 + lrow, n - 1) * d;
    const float* Kr = K + (size_t)b * sQ + (size_t)min(c0 + lrow, n - 1) * d;

    float acc[8][8] = {};
    for (int kk = 0; kk < d; kk += 16) {
        #pragma unroll
        for (int h = 0; h < 2; h++) {
            int g = kk + lk + h * 4;
            float4 qv = make_float4(0.f, 0.f, 0.f, 0.f);
            float4 kv = make_float4(0.f, 0.f, 0.f, 0.f);
            if (g + 4 <= d) {                 // d % 4 == 0 for all uses
                qv = *(const float4*)(Qr + g);
                kv = *(const float4*)(Kr + g);
            }
            int kb = lk + h * 4;
            Qs[kb + 0][lrow] = qv.x; Qs[kb + 1][lrow] = qv.y;
            Qs[kb + 2][lrow] = qv.z; Qs[kb + 3][lrow] = qv.w;
            Ks[kb + 0][lrow] = kv.x; Ks[kb + 1][lrow] = kv.y;
            Ks[kb + 2][lrow] = kv.z; Ks[kb + 3][lrow] = kv.w;
        }
        __syncthreads();
        #pragma unroll
        for (int k = 0; k < 16; k++) {
            float4 qa = *(const float4*)&Qs[k][ty * 8];
            float4 qb = *(const float4*)&Qs[k][ty * 8 + 4];
            float4 ka = *(const float4*)&Ks[k][tx * 8];
            float4 kb4 = *(const float4*)&Ks[k][tx * 8 + 4];
            float aq[8] = {qa.x, qa.y, qa.z, qa.w, qb.x, qb.y, qb.z, qb.w};
            float ak[8] = {ka.x, ka.y, ka.z, ka.w, kb4.x, kb4.y, kb4.z, kb4.w};
            #pragma unroll
            for (int i = 0; i < 8; i++)
                #pragma unroll
                for (int j = 0; j < 8; j++) acc[i][j] += aq[i] * ak[j];
        }
        __syncthreads();
    }
    float* Sb = S + (size_t)b * n * n;
    #pragma unroll
    for (int i = 0; i < 8; i++) {
        int r = r0 + ty * 8 + i;
        if (r < n) {
            #pragma unroll
            for (int j = 0; j < 8; j++) {
                int c = c0 + tx * 8 + j;
                if (c < n) Sb[(size_t)r * n + c] = acc[i][j];
            }
        }
    }
}

// ---------------------------------------------------------------------------
// 128-tile ABT: O[b,r,c] = sum_k A[b,r,k]*B[c,k]; B batch-shared; d-tail
// guarded scalar loads; cols [n,oLd) zero-filled.
// ---------------------------------------------------------------------------
__global__ void __launch_bounds__(256, 4)
k_abt128(const float* __restrict__ A, long long aBatch, int aLd,
         const float* __restrict__ B, int bLd,
         float* __restrict__ O, long long oBatch, int oLd, int n, int d) {
    __shared__ float Qs[16][132];
    __shared__ float Ks[16][132];
    int b  = blockIdx.z;
    int r0 = blockIdx.x * 128, c0 = blockIdx.y * 128;
    int tid = threadIdx.x;
    int tx = tid & 15, ty = tid >> 4;
    int lrow = tid >> 1;
    int lk   = (tid & 1) * 8;
    const float* Ar = A + (size_t)b * aBatch + (size_t)min(r0 + lrow, n - 1) * aLd;
    const float* Br = B + (size_t)min(c0 + lrow, n - 1) * bLd;

    float acc[8][8] = {};
    for (int kk = 0; kk < d; kk += 16) {
        #pragma unroll
        for (int h = 0; h < 2; h++) {
            int g = kk + lk + h * 4;
            float4 av, bv;
            if (g + 4 <= d) {
                av = *(const float4*)(Ar + g);
                bv = *(const float4*)(Br + g);
            } else {
                float ae[4], be[4];
                #pragma unroll
                for (int e = 0; e < 4; e++) {
                    int gg = g + e;
                    ae[e] = (gg < d) ? Ar[gg] : 0.f;
                    be[e] = (gg < d) ? Br[gg] : 0.f;
                }
                av = make_float4(ae[0], ae[1], ae[2], ae[3]);
                bv = make_float4(be[0], be[1], be[2], be[3]);
            }
            int kb = lk + h * 4;
            Qs[kb + 0][lrow] = av.x; Qs[kb + 1][lrow] = av.y;
            Qs[kb + 2][lrow] = av.z; Qs[kb + 3][lrow] = av.w;
            Ks[kb + 0][lrow] = bv.x; Ks[kb + 1][lrow] = bv.y;
            Ks[kb + 2][lrow] = bv.z; Ks[kb + 3][lrow] = bv.w;
        }
        __syncthreads();
        #pragma unroll
        for (int k = 0; k < 16; k++) {
            float4 qa = *(const float4*)&Qs[k][ty * 8];
            float4 qb = *(const float4*)&Qs[k][ty * 8 + 4];
            float4 ka = *(const float4*)&Ks[k][tx * 8];
            float4 kb4 = *(const float4*)&Ks[k][tx * 8 + 4];
            float aq[8] = {qa.x, qa.y, qa.z, qa.w, qb.x, qb.y, qb.z, qb.w};
            float ak[8] = {ka.x, ka.y, ka.z, ka.w, kb4.x, kb4.y, kb4.z, kb4.w};
            #pragma unroll
            for (int i = 0; i < 8; i++)
                #pragma unroll
                for (int j = 0; j < 8; j++) acc[i][j] += aq[i] * ak[j];
        }
        __syncthreads();
    }
    #pragma unroll
    for (int i = 0; i < 8; i++) {
        int r = r0 + ty * 8 + i;
        if (r < n) {
            #pragma unroll
            for (int j = 0; j < 8; j++) {
                int c = c0 + tx * 8 + j;
                if (c < oLd)
                    O[(size_t)b * oBatch + (size_t)r * oLd + c] = (c < n) ? acc[i][j] : 0.f;
            }
        }
    }
}

// ---------------------------------------------------------------------------
// f-branch scores split-K (n=58 fits a 64-tile).
// ---------------------------------------------------------------------------
__global__ void __launch_bounds__(256)
k_scores_sk(const float* __restrict__ Q, const float* __restrict__ K,
            float* __restrict__ SP, int n, int d, int kz_n, int chunk, int sQ) {
    __shared__ float Qs[16][68];
    __shared__ float Ks[16][68];
    int bz = blockIdx.z;
    int b  = bz / kz_n, kz = bz % kz_n;
    int k0 = kz * chunk, k1 = min(d, k0 + chunk);
    int r0 = blockIdx.x * 64, c0 = blockIdx.y * 64;
    int tx = threadIdx.x & 15, ty = threadIdx.x >> 4;
    int lrow = threadIdx.x >> 2;
    int lk   = (threadIdx.x & 3) * 4;
    const float* Qr = Q + (size_t)b * sQ + (size_t)min(r0 + lrow, n - 1) * d;
    const float* Kr = K + (size_t)b * sQ + (size_t)min(c0 + lrow, n - 1) * d;
    bool qok = (r0 + lrow) < n;
    bool kok = (c0 + lrow) < n;
    float acc[4][4] = {};

    for (int kk = k0; kk < k1; kk += 16) {
        #pragma unroll
        for (int u = 0; u < 4; u++) {
            int gk = kk + lk + u;
            bool gv = gk < k1;
            Qs[lk + u][lrow] = (qok && gv) ? Qr[gk] : 0.f;
            Ks[lk + u][lrow] = (kok && gv) ? Kr[gk] : 0.f;
        }
        __syncthreads();
        #pragma unroll
        for (int k = 0; k < 16; k++) {
            float4 q4 = *(const float4*)&Qs[k][ty * 4];
            float4 k4 = *(const float4*)&Ks[k][tx * 4];
            float aq[4] = {q4.x, q4.y, q4.z, q4.w};
            float ak[4] = {k4.x, k4.y, k4.z, k4.w};
            #pragma unroll
            for (int i = 0; i < 4; i++)
                #pragma unroll
                for (int j = 0; j < 4; j++) acc[i][j] += aq[i] * ak[j];
        }
        __syncthreads();
    }
    float* Sb = SP + (size_t)bz * n * n;
    #pragma unroll
    for (int i = 0; i < 4; i++) {
        int r = r0 + ty * 4 + i;
        #pragma unroll
        for (int j = 0; j < 4; j++) {
            int c = c0 + tx * 4 + j;
            if (r < n && c < n) Sb[(size_t)r * n + c] = acc[i][j];
        }
    }
}

// ---------------------------------------------------------------------------
// Small ABT (64-tile) for f/c gram transforms.
// ---------------------------------------------------------------------------
__global__ void __launch_bounds__(256)
k_abt(const float* __restrict__ A, long long aBatch, int aLd,
      const float* __restrict__ B, int bLd,
      float* __restrict__ O, long long oBatch, int oLd,
      int n, int d)
{
    __shared__ float Qs[16][68];
    __shared__ float Ks[16][68];
    int b  = blockIdx.z;
    int r0 = blockIdx.x * 64, c0 = blockIdx.y * 64;
    int tx = threadIdx.x & 15, ty = threadIdx.x >> 4;
    int lrow = threadIdx.x >> 2;
    int lk   = (threadIdx.x & 3) * 4;
    const float* Ar = A + (size_t)b * aBatch + (size_t)min(r0 + lrow, n - 1) * aLd;
    const float* Br = B + (size_t)min(c0 + lrow, n - 1) * bLd;
    bool aok = (r0 + lrow) < n;
    bool bok = (c0 + lrow) < n;
    float acc[4][4] = {};

    for (int kk = 0; kk < d; kk += 16) {
        #pragma unroll
        for (int u = 0; u < 4; u++) {
            int gk = kk + lk + u;
            bool gv = gk < d;
            Qs[lk + u][lrow] = (aok && gv) ? Ar[gk] : 0.f;
            Ks[lk + u][lrow] = (bok && gv) ? Br[gk] : 0.f;
        }
        __syncthreads();
        #pragma unroll
        for (int k = 0; k < 16; k++) {
            float4 q4 = *(const float4*)&Qs[k][ty * 4];
            float4 k4 = *(const float4*)&Ks[k][tx * 4];
            float aq[4] = {q4.x, q4.y, q4.z, q4.w};
            float ak[4] = {k4.x, k4.y, k4.z, k4.w};
            #pragma unroll
            for (int i = 0; i < 4; i++)
                #pragma unroll
                for (int j = 0; j < 4; j++) acc[i][j] += aq[i] * ak[j];
        }
        __syncthreads();
    }
    #pragma unroll
    for (int i = 0; i < 4; i++) {
        int r = r0 + ty * 4 + i;
        #pragma unroll
        for (int j = 0; j < 4; j++) {
            int c = c0 + tx * 4 + j;
            if (r < n && c < oLd)
                O[(size_t)b * oBatch + (size_t)r * oLd + c] = (c < n) ? acc[i][j] : 0.f;
        }
    }
}

// ---------------------------------------------------------------------------
// Row sums of Q and K views: sigma[b,r] = sum_l X[b*CFT + r*d + l]
// ---------------------------------------------------------------------------
__global__ void k_rowsum2(const float* __restrict__ Q, const float* __restrict__ K,
                          int n, int d, float* __restrict__ sQ, float* __restrict__ sK) {
    int b = blockIdx.x / n, r = blockIdx.x % n;
    const float* q = Q + (size_t)b * CFT + (size_t)r * d;
    const float* k = K + (size_t)b * CFT + (size_t)r * d;
    float s1 = 0.f, s2 = 0.f;
    for (int i = threadIdx.x; i < d; i += 256) { s1 += q[i]; s2 += k[i]; }
    __shared__ float red[2][256];
    red[0][threadIdx.x] = s1; red[1][threadIdx.x] = s2;
    __syncthreads();
    for (int s = 128; s > 0; s >>= 1) {
        if (threadIdx.x < s) {
            red[0][threadIdx.x] += red[0][threadIdx.x + s];
            red[1][threadIdx.x] += red[1][threadIdx.x + s];
        }
        __syncthreads();
    }
    if (threadIdx.x == 0) {
        sQ[(size_t)b * n + r] = red[0][0];
        sK[(size_t)b * n + r] = red[1][0];
    }
}

// ---------------------------------------------------------------------------
// u = Wq * sigmaQ ; v = Wk * sigmaK   (per batch)
// ---------------------------------------------------------------------------
__global__ void __launch_bounds__(256)
k_matvec2(const float* __restrict__ Wq, const float* __restrict__ Wk,
          const float* __restrict__ sQ, const float* __restrict__ sK,
          float* __restrict__ u, float* __restrict__ v, int n) {
    int b = blockIdx.x;
    __shared__ float sq[256], sk[256];
    for (int i = threadIdx.x; i < n; i += 256) {
        sq[i] = sQ[(size_t)b * n + i];
        sk[i] = sK[(size_t)b * n + i];
    }
    __syncthreads();
    for (int r = threadIdx.x; r < n; r += 256) {
        float a = 0.f, bb = 0.f;
        for (int m = 0; m < n; m++) {
            a  += Wq[(size_t)r * n + m] * sq[m];
            bb += Wk[(size_t)r * n + m] * sk[m];
        }
        u[(size_t)b * n + r] = a;
        v[(size_t)b * n + r] = bb;
    }
}

// ---------------------------------------------------------------------------
// Combine split-K partials.
// ---------------------------------------------------------------------------
__global__ void k_scombine(const float* __restrict__ SP, float* __restrict__ S,
                           int n, int kz_n) {
    int idx = blockIdx.x * 256 + threadIdx.x;
    int nn = n * n;
    if (idx >= Bn * nn) return;
    int b = idx / nn, rc = idx % nn;
    float s = 0.f;
    for (int kz = 0; kz < kz_n; kz++) s += SP[((size_t)b * kz_n + kz) * nn + rc];
    S[(size_t)b * nn + rc] = s;
}

// ---------------------------------------------------------------------------
// c-branch gram: 8x8 over d=FT, 8 l-chunks of partials.
// ---------------------------------------------------------------------------
#define C_LZ 8
__global__ void k_gram8(const float* __restrict__ Q, const float* __restrict__ K,
                        float* __restrict__ SP) {
    int b  = blockIdx.x / C_LZ;
    int lz = blockIdx.x % C_LZ;
    int g  = threadIdx.x >> 6;
    int p  = threadIdx.x & 63;
    int r  = p >> 3, c = p & 7;
    const float* Qb = Q + (size_t)b * CFT + (size_t)r * FT;
    const float* Kb = K + (size_t)b * CFT + (size_t)c * FT;
    int chunk = (FT + C_LZ - 1) / C_LZ;
    int l0 = lz * chunk, l1 = min(FT, l0 + chunk);
    float acc = 0.f;
    for (int l = l0 + g; l < l1; l += 4) acc += Qb[l] * Kb[l];
    __shared__ float red[256];
    red[threadIdx.x] = acc;
    __syncthreads();
    if (threadIdx.x < 64) {
        float s = red[p] + red[64 + p] + red[128 + p] + red[192 + p];
        SP[(size_t)blockIdx.x * 64 + p] = s;
    }
}

// ---------------------------------------------------------------------------
// Dual column softmax: Sacc = softmax(S1) + softmax(S2 + rank1).
// ---------------------------------------------------------------------------
__global__ void __launch_bounds__(256)
k_softmax2(const float* __restrict__ S1, long long b1, int ld1,
           const float* __restrict__ S2, long long b2, int ld2,
           float* __restrict__ Sacc, long long aB,
           int n, int cb, float scale,
           const float* __restrict__ bq, const float* __restrict__ u,
           const float* __restrict__ vv, const float* __restrict__ bk, float dlen) {
    __shared__ float redA[4][64];
    __shared__ float redB[4][64];
    int b  = blockIdx.x / cb;
    int tc = threadIdx.x & 63;
    int g  = threadIdx.x >> 6;
    int c  = (blockIdx.x % cb) * 64 + tc;
    bool act = c < n;
    const float* A1 = S1 + (size_t)b * b1;
    const float* A2 = S2 + (size_t)b * b2;
    const float* ub = u + (size_t)b * n;
    float alpha = 0.f, beta = 0.f;
    if (act) {
        beta  = bk[c];
        alpha = vv[(size_t)b * n + c] + dlen * beta;
    }
    auto V1 = [&](int r) { return A1[(size_t)r * ld1 + c]; };
    auto V2 = [&](int r) { return A2[(size_t)r * ld2 + c] + bq[r] * alpha + ub[r] * beta; };

    float m1 = -1e30f, m2 = -1e30f;
    if (act) for (int r = g; r < n; r += 4) {
        m1 = fmaxf(m1, V1(r)); m2 = fmaxf(m2, V2(r));
    }
    redA[g][tc] = m1; redB[g][tc] = m2;
    __syncthreads();
    m1 = fmaxf(fmaxf(redA[0][tc], redA[1][tc]), fmaxf(redA[2][tc], redA[3][tc]));
    m2 = fmaxf(fmaxf(redB[0][tc], redB[1][tc]), fmaxf(redB[2][tc], redB[3][tc]));
    __syncthreads();

    float s1 = 0.f, s2 = 0.f;
    if (act) for (int r = g; r < n; r += 4) {
        s1 += __expf((V1(r) - m1) * scale);
        s2 += __expf((V2(r) - m2) * scale);
    }
    redA[g][tc] = s1; redB[g][tc] = s2;
    __syncthreads();
    float i1 = 1.f / (redA[0][tc] + redA[1][tc] + redA[2][tc] + redA[3][tc]);
    float i2 = 1.f / (redB[0][tc] + redB[1][tc] + redB[2][tc] + redB[3][tc]);
    if (act) {
        float* Ab = Sacc + (size_t)b * aB;
        for (int r = g; r < n; r += 4) {
            Ab[(size_t)r * n + c] = __expf((V1(r) - m1) * scale) * i1
                                  + __expf((V2(r) - m2) * scale) * i2;
        }
    }
}

// ---------------------------------------------------------------------------
// Column softmax (single matrix), optional rank-1, Sacc accumulate or
// in-place destructive.
// ---------------------------------------------------------------------------
__global__ void __launch_bounds__(256)
k_softmax(float* __restrict__ S, long long sBatch, int ldS,
          float* __restrict__ Sacc, long long aBatch,
          int n, int cb, float scale, int first,
          const float* __restrict__ bq, const float* __restrict__ u,
          const float* __restrict__ vv, const float* __restrict__ bk,
          float dlen) {
    __shared__ float red[4][64];
    int b  = blockIdx.x / cb;
    int tc = threadIdx.x & 63;
    int g  = threadIdx.x >> 6;
    int c  = (blockIdx.x % cb) * 64 + tc;
    bool act = c < n;
    float* Sb = S + (size_t)b * sBatch;
    bool r1 = (bq != nullptr);
    const float* ub = r1 ? u + (size_t)b * n : nullptr;
    float alpha = 0.f, beta = 0.f;
    if (r1 && act) {
        beta  = bk[c];
        alpha = vv[(size_t)b * n + c] + dlen * beta;
    }
    auto VAL = [&](int r) {
        float s = Sb[(size_t)r * ldS + c];
        if (r1) s += bq[r] * alpha + ub[r] * beta;
        return s;
    };

    float mx = -1e30f;
    if (act) for (int r = g; r < n; r += 4) mx = fmaxf(mx, VAL(r));
    red[g][tc] = mx;
    __syncthreads();
    mx = fmaxf(fmaxf(red[0][tc], red[1][tc]), fmaxf(red[2][tc], red[3][tc]));
    __syncthreads();

    float sum = 0.f;
    if (act) {
        if (Sacc) {
            for (int r = g; r < n; r += 4) sum += __expf((VAL(r) - mx) * scale);
        } else {
            for (int r = g; r < n; r += 4) {
                float e = __expf((VAL(r) - mx) * scale);
                Sb[(size_t)r * ldS + c] = e;
                sum += e;
            }
        }
    }
    red[g][tc] = sum;
    __syncthreads();
    float inv = 1.f / (red[0][tc] + red[1][tc] + red[2][tc] + red[3][tc]);
    if (act) {
        if (Sacc) {
            float* Ab = Sacc + (size_t)b * aBatch;
            for (int r = g; r < n; r += 4) {
                float e = __expf((VAL(r) - mx) * scale) * inv;
                size_t o = (size_t)r * n + c;
                Ab[o] = first ? e : (Ab[o] + e);
            }
        } else {
            for (int r = g; r < n; r += 4) Sb[(size_t)r * ldS + c] *= inv;
        }
    }
}

// ---------------------------------------------------------------------------
// xr spatial mean per (b, rc)
// ---------------------------------------------------------------------------
__global__ void k_mean(const float* __restrict__ inp, const float* __restrict__ w_res,
                       const float* __restrict__ b_res, const float* __restrict__ bn_gamma,
                       const float* __restrict__ bn_beta, const float* __restrict__ bn_mean,
                       const float* __restrict__ bn_var, float* __restrict__ meanbuf) {
    int b  = blockIdx.x / RCn;
    int rc = blockIdx.x % RCn;
    float w[9];
    #pragma unroll
    for (int i = 0; i < 9; i++) w[i] = w_res[rc * 9 + i];
    float g    = bn_gamma[rc] * rsqrtf(bn_var[rc] + 1e-5f);
    float bias = (b_res[rc] - bn_mean[rc]) * g + bn_beta[rc];
    const float* ib = inp + (size_t)b * IH * IW;

    float sum = 0.f;
    for (int idx = threadIdx.x; idx < FT; idx += 256) {
        int f = idx / Tn, t = idx % Tn;
        const float* p = ib + f * IW + t;
        float v = w[0]*p[0]     + w[1]*p[1]     + w[2]*p[2]
                + w[3]*p[IW]    + w[4]*p[IW+1]  + w[5]*p[IW+2]
                + w[6]*p[2*IW]  + w[7]*p[2*IW+1]+ w[8]*p[2*IW+2];
        sum += v * g + bias;
    }
    __shared__ float red[256];
    red[threadIdx.x] = sum;
    __syncthreads();
    for (int s = 128; s > 0; s >>= 1) {
        if (threadIdx.x < s) red[threadIdx.x] += red[threadIdx.x + s];
        __syncthreads();
    }
    if (threadIdx.x == 0) meanbuf[b * RCn + rc] = red[0] / (float)FT;
}

// ---------------------------------------------------------------------------
// dyReLU coefficient MLP
// ---------------------------------------------------------------------------
__global__ void k_coef(const float* __restrict__ meanbuf, const float* __restrict__ w1,
                       const float* __restrict__ b1, const float* __restrict__ w2,
                       const float* __restrict__ b2, float* __restrict__ coef) {
    int b = blockIdx.x;
    int k = threadIdx.x;
    if (k >= 4 * RCn) return;
    const float* th = meanbuf + b * RCn;
    float h[6];
    #pragma unroll
    for (int j = 0; j < 6; j++) {
        float s = b1[j];
        #pragma unroll
        for (int c = 0; c < RCn; c++) s += th[c] * w1[j * RCn + c];
        h[j] = fmaxf(s, 0.f);
    }
    float s = b2[k];
    #pragma unroll
    for (int j = 0; j < 6; j++) s += h[j] * w2[k * 6 + j];
    float g2 = 2.f / (1.f + __expf(-s)) - 1.f;
    const float lam[4] = {1.f, 1.f, 0.5f, 0.5f};
    const float ini[4] = {1.f, 0.f, 0.f, 0.f};
    coef[b * 96 + k] = g2 * lam[k & 3] + ini[k & 3];
}

// ---------------------------------------------------------------------------
// recompute conv+BN, apply dyReLU, out += xr. Grid (Fn, RCn, Bn), zero div/mod.
// ---------------------------------------------------------------------------
__global__ void __launch_bounds__(256)
k_xr_add(const float* __restrict__ inp, const float* __restrict__ w_res,
         const float* __restrict__ b_res, const float* __restrict__ bn_gamma,
         const float* __restrict__ bn_beta, const float* __restrict__ bn_mean,
         const float* __restrict__ bn_var, const float* __restrict__ coef,
         float* __restrict__ out) {
    int t  = threadIdx.x;
    if (t >= Tn) return;
    int f  = blockIdx.x;
    int rc = blockIdx.y;
    int b  = blockIdx.z;

    const float* wp = w_res + rc * 9;
    float g    = bn_gamma[rc] * rsqrtf(bn_var[rc] + 1e-5f);
    float bias = (b_res[rc] - bn_mean[rc]) * g + bn_beta[rc];
    const float* cf = coef + ((size_t)b * RCn + rc) * 4;
    float c0 = cf[0], c1 = cf[1], c2 = cf[2], c3 = cf[3];

    const float* p = inp + (size_t)b * IH * IW + f * IW + t;
    float v = wp[0]*p[0]    + wp[1]*p[1]      + wp[2]*p[2]
            + wp[3]*p[IW]   + wp[4]*p[IW+1]   + wp[5]*p[IW+2]
            + wp[6]*p[2*IW] + wp[7]*p[2*IW+1] + wp[8]*p[2*IW+2];
    float xv = v * g + bias;
    float r = fmaxf(xv * c0 + c2, xv * c1 + c3);
    out[(size_t)b * OUTB + (size_t)rc * FT + (size_t)f * Tn + t] += r;
}

// ---------------------------------------------------------------------------
extern "C" void kernel_launch(void* const* d_in, const int* in_sizes, int n_in,
                              void* d_out, int out_size, void* d_ws, size_t ws_size,
                              hipStream_t stream) {
    const float* x        = (const float*)d_in[0];
    const float* inp      = (const float*)d_in[1];
    const float* w_diff   = (const float*)d_in[2];
    const float* b_diff   = (const float*)d_in[3];
    const float* w_res    = (const float*)d_in[4];
    const float* b_res    = (const float*)d_in[5];
    const float* bn_gamma = (const float*)d_in[6];
    const float* bn_beta  = (const float*)d_in[7];
    const float* bn_mean  = (const float*)d_in[8];
    const float* bn_var   = (const float*)d_in[9];
    const float* dy_w1    = (const float*)d_in[10];
    const float* dy_b1    = (const float*)d_in[11];
    const float* dy_w2    = (const float*)d_in[12];
    const float* dy_b2    = (const float*)d_in[13];
    const float* wq       = (const float*)d_in[14];
    const float* bq       = (const float*)d_in[15];
    const float* wk       = (const float*)d_in[16];
    const float* bk       = (const float*)d_in[17];
    const float* fq0_w    = (const float*)d_in[18];
    const float* fq0_b    = (const float*)d_in[19];
    const float* fk0_w    = (const float*)d_in[20];
    const float* fk0_b    = (const float*)d_in[21];
    const float* cq0_w    = (const float*)d_in[22];
    const float* cq0_b    = (const float*)d_in[23];
    const float* ck0_w    = (const float*)d_in[24];
    const float* ck0_b    = (const float*)d_in[25];
    const float* tq0_w    = (const float*)d_in[26];
    const float* tq0_b    = (const float*)d_in[27];
    const float* tk0_w    = (const float*)d_in[28];
    const float* tk0_b    = (const float*)d_in[29];
    const float* tq1_w    = (const float*)d_in[30];
    const float* tq1_b    = (const float*)d_in[31];
    const float* tk1_w    = (const float*)d_in[32];
    const float* tk1_b    = (const float*)d_in[33];

    float* out = (float*)d_out;
    float* ws  = (float*)d_ws;

    const size_t NB  = (size_t)Bn * CFT;
    const size_t SNN = (size_t)Bn * Tn * Tn;          // 7,936,128 floats
    float* V       = ws;
    float* Q       = ws + NB;
    float* K       = ws + 2 * NB;
    float* Qp      = ws + 3 * NB;
    float* Kp      = ws + 4 * NB;
    float* S       = ws + 5 * NB;                     // SNN floats
    float* meanbuf = S + SNN;
    float* coef    = meanbuf + 3072;
    float* SaccT   = coef + 12288;                    // SNN, only if fuseT
    // scratch inside existing regions (per-branch lifetimes, sequential):
    float* T2f   = S + 1000000;      // f/c: T2 (ld 60 / ld 8)
    float* S2f   = S + 2000000;      // f/c: S2
    float* SaccF = S + 3000000;      // f P-sum (430,592)
    float* SaccC = S + 3500000;      // c P-sum (8,192)
    float* SPp   = S + 4000000;      // split-K / gram partials (3.44M)
    // t-branch re-homing: Q,K die after the s2 convs + rowsum2, so T2 lives
    // in the Q region and S2 in the K region; conv outputs take Qp/Kp.
    float* T2t   = Q;                // 249*252*128 = 8.03M <= NB
    float* S2t   = K;
    float* sg    = Kp + 9000000;     // sigma/u/v block (Kp tail; conv-k uses <7.4M)
    float *sQt = sg,          *sKt = sg + 32000,  *ut = sg + 64000,  *vt = sg + 96000;
    float *sQf = sg + 128000, *sKf = sg + 136000, *uf = sg + 144000, *vf = sg + 152000;
    float *sQc = sg + 160000, *sKc = sg + 161024, *uc = sg + 162048, *vc = sg + 163072;
    bool fuseT = ws_size >= (5 * NB + 2 * SNN + 15360) * sizeof(float);

    k_differ_qk<<<dim3(1, Fn, Bn), dim3(256), 0, stream>>>(
        x, w_diff, b_diff, wq, bq, wk, bk, V, Q, K);

    const float scF   = 1.0f / sqrtf(1992.f);
    const float scC   = 1.0f / sqrtf((float)FT);
    const float sc464 = 1.0f / sqrtf(464.f);
    const float sc232 = 1.0f / sqrtf(232.f);

    // ======== f branch (n=58, d=1992, sec=0) — gram transform ========
    {
        dim3 g1(1, 1, Bn * 8);
        k_scores_sk<<<g1, dim3(256), 0, stream>>>(Q, K, SPp, Fn, 1992, 8, 256, CFT);
        k_scombine<<<dim3((Bn * Fn * Fn + 255) / 256), dim3(256), 0, stream>>>(SPp, S, Fn, 8);
        k_rowsum2<<<dim3(Bn * Fn), dim3(256), 0, stream>>>(Q, K, Fn, 1992, sQf, sKf);
        k_matvec2<<<dim3(Bn), dim3(256), 0, stream>>>(fq0_w, fk0_w, sQf, sKf, uf, vf, Fn);
        k_abt<<<dim3(1, 1, Bn), dim3(256), 0, stream>>>(S, 3364, Fn, fk0_w, Fn,
                                                        T2f, 3480, 60, Fn, Fn);
        k_gemm<Fn, 8, 4, 4><<<dim3(Bn * 2), dim3(256), 0, stream>>>(
            fq0_w, 0, Fn, nullptr, T2f, 3480, 60, S2f, 3480, 0, 1, 2);
        k_softmax2<<<dim3(Bn), dim3(256), 0, stream>>>(
            S, 3364, Fn, S2f, 3480, 60, SaccF, 3364, Fn, 1, scF,
            fq0_b, uf, vf, fk0_b, 1992.f);
        k_gemm<Fn, 15, 2, 4><<<dim3(Bn * 8), dim3(256), 0, stream>>>(
            SaccF, 3364, Fn, nullptr, V, CFT, 1992, out, OUTB, 0, 4, 2);
    }

    // ======== c branch (n=8, d=FT, sec=1) — gram transform ========
    {
        k_gram8<<<dim3(Bn * C_LZ), dim3(256), 0, stream>>>(Q, K, SPp);
        k_scombine<<<dim3((Bn * 64 + 255) / 256), dim3(256), 0, stream>>>(SPp, S, Cn, C_LZ);
        k_rowsum2<<<dim3(Bn * Cn), dim3(256), 0, stream>>>(Q, K, Cn, FT, sQc, sKc);
        k_matvec2<<<dim3(Bn), dim3(256), 0, stream>>>(cq0_w, ck0_w, sQc, sKc, uc, vc, Cn);
        k_abt<<<dim3(1, 1, Bn), dim3(256), 0, stream>>>(S, 64, Cn, ck0_w, Cn,
                                                        T2f, 64, 8, Cn, Cn);
        k_gemm<Cn, 8, 1, 2><<<dim3(Bn), dim3(256), 0, stream>>>(
            cq0_w, 0, Cn, nullptr, T2f, 64, 8, S2f, 64, 0, 1, 1);
        k_softmax2<<<dim3(Bn), dim3(256), 0, stream>>>(
            S, 64, Cn, S2f, 64, 8, SaccC, 64, Cn, 1, scC,
            cq0_b, uc, vc, ck0_b, (float)FT);
        k_gemm<Cn, 8, 1, 2><<<dim3(Bn * 29), dim3(256), 0, stream>>>(
            SaccC, 64, Cn, nullptr, V, CFT, FT, out + CFT, OUTB, 0, 29, 1);
    }

    // ======== t branch (n=249, dv=464, sec=2) ========
    {
        // 1) round-0 gram + rowsums (streams Q,K -> L3-warm)
        k_scores128<<<dim3(2, 2, Bn), dim3(256), 0, stream>>>(Q, K, S, Tn, 464, CFT);
        k_rowsum2<<<dim3(Bn * Tn), dim3(256), 0, stream>>>(Q, K, Tn, 464, sQt, sKt);
        // 2) stride-2 convs while Q/K are warm (R7 lesson). Outputs -> Qp/Kp.
        k_gemm_s2<Tn, 4><<<dim3(Bn * 16), dim3(256), 0, stream>>>(
            tq1_w, tq1_b, Q, CFT, 464, 232, Qp, (long long)Tn * 232, 16);
        k_gemm_s2<Tn, 4><<<dim3(Bn * 16), dim3(256), 0, stream>>>(
            tk1_w, tk1_b, K, CFT, 464, 232, Kp, (long long)Tn * 232, 16);
        // 3) gram transform: Q,K regions now dead -> host T2/S2 there.
        k_matvec2<<<dim3(Bn), dim3(256), 0, stream>>>(tq0_w, tk0_w, sQt, sKt, ut, vt, Tn);
        k_abt128<<<dim3(2, 2, Bn), dim3(256), 0, stream>>>(S, 62001, Tn, tk0_w, Tn,
                                                           T2t, 62748, 252, Tn, Tn);
        k_gemm<Tn, 8, 4, 4><<<dim3(Bn * 8), dim3(256), 0, stream>>>(
            tq0_w, 0, Tn, nullptr, T2t, 62748, 252, S2t, 62748, 0, 1, 8);
        if (fuseT) {
            k_softmax2<<<dim3(Bn * 4), dim3(256), 0, stream>>>(
                S, 62001, Tn, S2t, 62748, 252, SaccT, 62001, Tn, 4, sc464,
                tq0_b, ut, vt, tk0_b, 464.f);
            k_scores128<<<dim3(2, 2, Bn), dim3(256), 0, stream>>>(Qp, Kp, S, Tn, 232, Tn * 232);
            k_softmax<<<dim3(Bn * 4), dim3(256), 0, stream>>>(
                S, 62001, Tn, SaccT, 62001, Tn, 4, sc232, 0,
                nullptr, nullptr, nullptr, nullptr, 0.f);
            k_gemm<Tn, 16, 2, 4><<<dim3(Bn * 8), dim3(256), 0, stream>>>(
                SaccT, 62001, Tn, nullptr, V, CFT, 464, out + 2 * CFT, OUTB, 0, 1, 8);
        } else {
            k_softmax<<<dim3(Bn * 4), dim3(256), 0, stream>>>(
                S, 62001, Tn, nullptr, 0, Tn, 4, sc464, 0,
                nullptr, nullptr, nullptr, nullptr, 0.f);
            k_gemm<Tn, 16, 2, 4><<<dim3(Bn * 8), dim3(256), 0, stream>>>(
                S, 62001, Tn, nullptr, V, CFT, 464, out + 2 * CFT, OUTB, 0, 1, 8);
            k_softmax<<<dim3(Bn * 4), dim3(256), 0, stream>>>(
                S2t, 62748, 252, nullptr, 0, Tn, 4, sc464, 0,
                tq0_b, ut, vt, tk0_b, 464.f);
            k_gemm<Tn, 16, 2, 4><<<dim3(Bn * 8), dim3(256), 0, stream>>>(
                S2t, 62748, 252, nullptr, V, CFT, 464, out + 2 * CFT, OUTB, 1, 1, 8);
            k_scores128<<<dim3(2, 2, Bn), dim3(256), 0, stream>>>(Qp, Kp, S, Tn, 232, Tn * 232);
            k_softmax<<<dim3(Bn * 4), dim3(256), 0, stream>>>(
                S, 62001, Tn, nullptr, 0, Tn, 4, sc232, 0,
                nullptr, nullptr, nullptr, nullptr, 0.f);
            k_gemm<Tn, 16, 2, 4><<<dim3(Bn * 8), dim3(256), 0, stream>>>(
                S, 62001, Tn, nullptr, V, CFT, 464, out + 2 * CFT, OUTB, 1, 1, 8);
        }
    }

    // ---- xr residual path
    k_mean<<<dim3(Bn * RCn), dim3(256), 0, stream>>>(
        inp, w_res, b_res, bn_gamma, bn_beta, bn_mean, bn_var, meanbuf);
    k_coef<<<dim3(Bn), dim3(128), 0, stream>>>(meanbuf, dy_w1, dy_b1, dy_w2, dy_b2, coef);
    k_xr_add<<<dim3(Fn, RCn, Bn), dim3(256), 0, stream>>>(
        inp, w_res, b_res, bn_gamma, bn_beta, bn_mean, bn_var, coef, out);
}